// Round 8
// baseline (212.617 us; speedup 1.0000x reference)
//
#include <hip/hip_runtime.h>
#include <hip/hip_bf16.h>
#include <stdint.h>

#define B_ 4
#define L_ 2048
#define H_ 8
#define E_ 64
#define ALPHA 0.1f
#define LOG2E 1.44269504088896f
// Q prescale: 1/sqrt(64) * log2(e) folded into projected Q so P = exp2(S)
#define QSCALE (0.125f * LOG2E)
#define TSTR 72   // LDS tile row stride (elements)

typedef float f32x4 __attribute__((ext_vector_type(4)));
typedef short bf16x8 __attribute__((ext_vector_type(8)));
typedef short bf16x4 __attribute__((ext_vector_type(4)));
typedef uint32_t u32;
typedef unsigned short u16;
typedef u32 u32x2 __attribute__((ext_vector_type(2)));

// Workgroup barrier without the vmcnt(0) drain (LDS-drain only); in-flight
// global loads target per-thread VGPRs, compiler inserts vmcnt before use.
__device__ __forceinline__ void barrier_lds_only() {
    asm volatile("s_waitcnt lgkmcnt(0)\n\ts_barrier" ::: "memory");
}

__device__ __forceinline__ u16 f2bf(float f) {
    u32 x = __builtin_bit_cast(u32, f);
    u32 r = x + 0x7fffu + ((x >> 16) & 1u);   // round-to-nearest-even
    return (u16)(r >> 16);
}

// pack two positive floats to packed bf16 (round-half-up; P>0, never NaN)
__device__ __forceinline__ u32 pk2bf(float a, float b) {
    u32 ua = __builtin_bit_cast(u32, a) + 0x8000u;
    u32 ub = __builtin_bit_cast(u32, b) + 0x8000u;
    return (ua >> 16) | (ub & 0xffff0000u);
}

__device__ __forceinline__ f32x4 mfma16x16x16bf16(bf16x4 a, bf16x4 b, f32x4 c) {
#if __has_builtin(__builtin_amdgcn_mfma_f32_16x16x16bf16_1k)
    return __builtin_amdgcn_mfma_f32_16x16x16bf16_1k(a, b, c, 0, 0, 0);
#elif __has_builtin(__builtin_amdgcn_mfma_f32_16x16x16_bf16)
    return __builtin_amdgcn_mfma_f32_16x16x16_bf16(a, b, c, 0, 0, 0);
#else
    f32x4 d;
    asm volatile("v_mfma_f32_16x16x16_bf16 %0, %1, %2, %3"
                 : "=v"(d) : "v"(a), "v"(b), "v"(c));
    return d;
#endif
}

// ---------------------------------------------------------------------------
// Prep kernel (fused): projection Q,K -> bf16 [B*H,L,E]; V transpose -> bf16
// Vt [B*H,D,S]. (unchanged)
// ---------------------------------------------------------------------------
__global__ __launch_bounds__(256) void prep_kernel(const float* __restrict__ qin,
                                                   const float* __restrict__ kin,
                                                   const float* __restrict__ vin,
                                                   u16* __restrict__ qp,
                                                   u16* __restrict__ kp,
                                                   u16* __restrict__ vt) {
    __shared__ u16 tile[64][66];
    if (blockIdx.x < 4096) {
        const int RG = (B_ * L_ * H_) / 8;
        int wave = threadIdx.x >> 6, lane = threadIdx.x & 63;
        int g = blockIdx.x * 4 + wave;
        const float* src;
        u16* dst;
        int gr;
        float sc;
        if (g < RG) { src = qin; dst = qp; gr = g; sc = QSCALE; }
        else        { src = kin; dst = kp; gr = g - RG; sc = 1.0f; }

        int rig = lane >> 3;
        int c = (lane & 7) * 4;
        int row = gr * 8 + rig;

        const float* rp = src + (size_t)row * 64;
        float4 v0 = *(const float4*)(rp + c);
        float4 v1 = *(const float4*)(rp + c + 32);
        float f[8] = {v0.x, v0.y, v0.z, v0.w, v1.x, v1.y, v1.z, v1.w};

        float mx = 0.f;
#pragma unroll
        for (int i = 0; i < 8; ++i) mx = fmaxf(mx, fabsf(f[i]));
#pragma unroll
        for (int m = 1; m < 8; m <<= 1) mx = fmaxf(mx, __shfl_xor(mx, m));
        float thr = ALPHA * mx;

        u16 o[8];
#pragma unroll
        for (int i = 0; i < 8; ++i)
            o[i] = (fabsf(f[i]) >= thr) ? f2bf(f[i] * sc) : (u16)0;

        int b = row >> 14;
        int l = (row >> 3) & (L_ - 1);
        int h = row & 7;
        u16* orow = dst + ((size_t)(b * H_ + h) * L_ + l) * 64;
        uint2 p0 = {(u32)o[0] | ((u32)o[1] << 16), (u32)o[2] | ((u32)o[3] << 16)};
        uint2 p1 = {(u32)o[4] | ((u32)o[5] << 16), (u32)o[6] | ((u32)o[7] << 16)};
        *(uint2*)(orow + c) = p0;
        *(uint2*)(orow + c + 32) = p1;
    } else {
        int bx = blockIdx.x - 4096;
        int bh = bx >> 5, sblk = bx & 31;
        int b = bh >> 3, h = bh & 7;
        int t = threadIdx.x;
        int s0 = sblk * 64;

#pragma unroll
        for (int p = 0; p < 2; ++p) {
            int sl = p * 32 + (t >> 3);
            int c = (t & 7) * 4;
            const float* rp = vin + (((size_t)(b * L_ + s0 + sl)) * H_ + h) * 64;
            float4 a = *(const float4*)(rp + c);
            float4 bb = *(const float4*)(rp + c + 32);
            u32* d0 = (u32*)&tile[sl][c];
            d0[0] = (u32)f2bf(a.x) | ((u32)f2bf(a.y) << 16);
            d0[1] = (u32)f2bf(a.z) | ((u32)f2bf(a.w) << 16);
            u32* d1 = (u32*)&tile[sl][c + 32];
            d1[0] = (u32)f2bf(bb.x) | ((u32)f2bf(bb.y) << 16);
            d1[1] = (u32)f2bf(bb.z) | ((u32)f2bf(bb.w) << 16);
        }
        __syncthreads();
#pragma unroll
        for (int p = 0; p < 2; ++p) {
            int d = p * 32 + (t >> 3);
            int sc2 = (t & 7) * 8;
            u16 o[8];
#pragma unroll
            for (int i = 0; i < 8; ++i) o[i] = tile[sc2 + i][d];
            uint4 val;
            val.x = (u32)o[0] | ((u32)o[1] << 16);
            val.y = (u32)o[2] | ((u32)o[3] << 16);
            val.z = (u32)o[4] | ((u32)o[5] << 16);
            val.w = (u32)o[6] | ((u32)o[7] << 16);
            *(uint4*)(vt + ((size_t)bh * 64 + d) * L_ + s0 + sc2) = val;
        }
    }
}

// ---------------------------------------------------------------------------
// Flash attention v8: each wave owns 32 q-rows as two 16-row fragments
// (A at qg*128+16w, B at +64) -> two independent S->exp->PV streams per wave,
// K/V LDS reads amortized 2x, barriers per unit work halved.
// Grid: 512 = 16 qg (descending, longest first) x 32 bh; 2 blocks/CU pair
// long+short (34-36 tiles/CU). Double-buffered LDS staging as before.
// Diagonal mask is lane-local: quad*4+r > lo (frag A at tile 2qg, frag B at
// tile 2qg+1, both at subtile w).
// ---------------------------------------------------------------------------
__global__ __launch_bounds__(256, 2) void flash_kernel(const u16* __restrict__ Qp,
                                                       const u16* __restrict__ Kp,
                                                       const u16* __restrict__ Vt,
                                                       float* __restrict__ out) {
    __shared__ u16 kbuf[2][64 * TSTR];   // 2 x 9216 B
    __shared__ u16 vbuf[2][64 * TSTR];   // 2 x 9216 B
    int t = threadIdx.x;
    int wave = t >> 6, lane = t & 63;
    int bh = blockIdx.x & 31;
    int qg = 15 - (blockIdx.x >> 5);     // descending: longest blocks first
    int lo = lane & 15, quad = lane >> 4;
    int b = bh >> 3, h = bh & 7;
    int qA = qg * 128 + wave * 16;       // frag A rows
    int qB = qA + 64;                    // frag B rows
    int dA = qg * 2;                     // frag A diagonal tile
    int T = dA + 1;                      // last tile (frag B diagonal)

    const u16* kbase = Kp + (size_t)bh * L_ * 64;
    const u16* vbase = Vt + (size_t)bh * 64 * L_;
    int r0 = t >> 3, ch = t & 7;         // staging: rows r0,r0+32, 16B chunk ch

    const u16* qbA = Qp + ((size_t)bh * L_ + qA + lo) * 64 + quad * 8;
    bf16x8 aQA0 = *(const bf16x8*)(qbA);
    bf16x8 aQA1 = *(const bf16x8*)(qbA + 32);
    const u16* qbB = Qp + ((size_t)bh * L_ + qB + lo) * 64 + quad * 8;
    bf16x8 aQB0 = *(const bf16x8*)(qbB);
    bf16x8 aQB1 = *(const bf16x8*)(qbB + 32);

    f32x4 oA[4], oB[4];
#pragma unroll
    for (int ni = 0; ni < 4; ++ni) {
        oA[ni] = (f32x4){0.f, 0.f, 0.f, 0.f};
        oB[ni] = (f32x4){0.f, 0.f, 0.f, 0.f};
    }
    float lsA = 0.f, lsB = 0.f;

    auto frag_proc = [&](bf16x8 k0, bf16x8 k1, const bf16x4* vf,
                         bf16x8 fq0, bf16x8 fq1, f32x4* oacc, float& lsacc,
                         bool diag) {
        f32x4 S = {0.f, 0.f, 0.f, 0.f};
        S = __builtin_amdgcn_mfma_f32_16x16x32_bf16(k0, fq0, S, 0, 0, 0);
        S = __builtin_amdgcn_mfma_f32_16x16x32_bf16(k1, fq1, S, 0, 0, 0);
        float P[4];
#pragma unroll
        for (int r = 0; r < 4; ++r) {
            float e = __builtin_amdgcn_exp2f(S[r]);
            P[r] = (diag && (quad * 4 + r > lo)) ? 0.f : e;
        }
        lsacc += (P[0] + P[1]) + (P[2] + P[3]);
        u32x2 pk = {pk2bf(P[0], P[1]), pk2bf(P[2], P[3])};
        bf16x4 aP = __builtin_bit_cast(bf16x4, pk);
#pragma unroll
        for (int ni = 0; ni < 4; ++ni)
            oacc[ni] = mfma16x16x16bf16(aP, vf[ni], oacc[ni]);
    };

    uint4 kreg[2], vreg[2];
    // ---- prologue: tile 0 -> LDS buf0; tile 1 loads -> regs ----
    kreg[0] = *(const uint4*)(kbase + (size_t)t * 8);
    kreg[1] = *(const uint4*)(kbase + (size_t)(256 + t) * 8);
    vreg[0] = *(const uint4*)(vbase + (size_t)r0 * L_ + ch * 8);
    vreg[1] = *(const uint4*)(vbase + (size_t)(r0 + 32) * L_ + ch * 8);
    *(uint4*)(&kbuf[0][r0 * TSTR + ch * 8]) = kreg[0];
    *(uint4*)(&kbuf[0][(r0 + 32) * TSTR + ch * 8]) = kreg[1];
    *(uint4*)(&vbuf[0][r0 * TSTR + ch * 8]) = vreg[0];
    *(uint4*)(&vbuf[0][(r0 + 32) * TSTR + ch * 8]) = vreg[1];
    kreg[0] = *(const uint4*)(kbase + (size_t)64 * 64 + t * 8);
    kreg[1] = *(const uint4*)(kbase + (size_t)64 * 64 + (256 + t) * 8);
    vreg[0] = *(const uint4*)(vbase + (size_t)r0 * L_ + 64 + ch * 8);
    vreg[1] = *(const uint4*)(vbase + (size_t)(r0 + 32) * L_ + 64 + ch * 8);
    barrier_lds_only();

    // ---- full tiles 0..dA-1: both frags, all 4 subtiles ----
    for (int kt = 0; kt < dA; ++kt) {
        int cur = kt & 1;
        u16* kd = kbuf[cur ^ 1];
        u16* vd = vbuf[cur ^ 1];
        *(uint4*)(&kd[r0 * TSTR + ch * 8]) = kreg[0];
        *(uint4*)(&kd[(r0 + 32) * TSTR + ch * 8]) = kreg[1];
        *(uint4*)(&vd[r0 * TSTR + ch * 8]) = vreg[0];
        *(uint4*)(&vd[(r0 + 32) * TSTR + ch * 8]) = vreg[1];
        {   // load tile kt+2 (kt+2 <= T always inside this loop)
            size_t sb2 = (size_t)(kt + 2) << 6;
            kreg[0] = *(const uint4*)(kbase + sb2 * 64 + t * 8);
            kreg[1] = *(const uint4*)(kbase + sb2 * 64 + (256 + t) * 8);
            vreg[0] = *(const uint4*)(vbase + (size_t)r0 * L_ + sb2 + ch * 8);
            vreg[1] = *(const uint4*)(vbase + (size_t)(r0 + 32) * L_ + sb2 + ch * 8);
        }
        const u16* ks = kbuf[cur];
        const u16* vs = vbuf[cur];
#pragma unroll
        for (int sub = 0; sub < 4; ++sub) {
            bf16x8 k0 = *(const bf16x8*)(ks + (sub * 16 + lo) * TSTR + quad * 8);
            bf16x8 k1 = *(const bf16x8*)(ks + (sub * 16 + lo) * TSTR + 32 + quad * 8);
            bf16x4 vf[4];
#pragma unroll
            for (int ni = 0; ni < 4; ++ni)
                vf[ni] = *(const bf16x4*)(vs + (ni * 16 + lo) * TSTR + sub * 16 + quad * 4);
            frag_proc(k0, k1, vf, aQA0, aQA1, oA, lsA, false);
            frag_proc(k0, k1, vf, aQB0, aQB1, oB, lsB, false);
        }
        barrier_lds_only();
    }

    // ---- tile dA: frag A diagonal (subs 0..w), frag B full; stage tile T ----
    {
        int cur = dA & 1;
        u16* kd = kbuf[cur ^ 1];
        u16* vd = vbuf[cur ^ 1];
        *(uint4*)(&kd[r0 * TSTR + ch * 8]) = kreg[0];
        *(uint4*)(&kd[(r0 + 32) * TSTR + ch * 8]) = kreg[1];
        *(uint4*)(&vd[r0 * TSTR + ch * 8]) = vreg[0];
        *(uint4*)(&vd[(r0 + 32) * TSTR + ch * 8]) = vreg[1];
        const u16* ks = kbuf[cur];
        const u16* vs = vbuf[cur];
#pragma unroll
        for (int sub = 0; sub < 4; ++sub) {
            bf16x8 k0 = *(const bf16x8*)(ks + (sub * 16 + lo) * TSTR + quad * 8);
            bf16x8 k1 = *(const bf16x8*)(ks + (sub * 16 + lo) * TSTR + 32 + quad * 8);
            bf16x4 vf[4];
#pragma unroll
            for (int ni = 0; ni < 4; ++ni)
                vf[ni] = *(const bf16x4*)(vs + (ni * 16 + lo) * TSTR + sub * 16 + quad * 4);
            frag_proc(k0, k1, vf, aQB0, aQB1, oB, lsB, false);
            if (sub < wave)
                frag_proc(k0, k1, vf, aQA0, aQA1, oA, lsA, false);
            else if (sub == wave)
                frag_proc(k0, k1, vf, aQA0, aQA1, oA, lsA, true);
        }
        barrier_lds_only();
    }

    // ---- tile T: frag B diagonal only (subs 0..w); no trailing barrier ----
    {
        int cur = T & 1;
        const u16* ks = kbuf[cur];
        const u16* vs = vbuf[cur];
        for (int sub = 0; sub < wave; ++sub) {
            bf16x8 k0 = *(const bf16x8*)(ks + (sub * 16 + lo) * TSTR + quad * 8);
            bf16x8 k1 = *(const bf16x8*)(ks + (sub * 16 + lo) * TSTR + 32 + quad * 8);
            bf16x4 vf[4];
#pragma unroll
            for (int ni = 0; ni < 4; ++ni)
                vf[ni] = *(const bf16x4*)(vs + (ni * 16 + lo) * TSTR + sub * 16 + quad * 4);
            frag_proc(k0, k1, vf, aQB0, aQB1, oB, lsB, false);
        }
        {
            int sub = wave;
            bf16x8 k0 = *(const bf16x8*)(ks + (sub * 16 + lo) * TSTR + quad * 8);
            bf16x8 k1 = *(const bf16x8*)(ks + (sub * 16 + lo) * TSTR + 32 + quad * 8);
            bf16x4 vf[4];
#pragma unroll
            for (int ni = 0; ni < 4; ++ni)
                vf[ni] = *(const bf16x4*)(vs + (ni * 16 + lo) * TSTR + sub * 16 + quad * 4);
            frag_proc(k0, k1, vf, aQB0, aQB1, oB, lsB, true);
        }
    }

    // ---- epilogue per fragment ----
    auto epi = [&](float ls, const f32x4* oacc, int q0f) {
        ls += __shfl_xor(ls, 16);
        ls += __shfl_xor(ls, 32);
#pragma unroll
        for (int r = 0; r < 4; ++r) {
            float lr = __shfl(ls, quad * 4 + r);
            float inv = 1.0f / lr;
            int q = q0f + quad * 4 + r;
            float* ob = out + (((size_t)(b * L_ + q)) * H_ + h) * 64 + lo;
            ob[0]  = oacc[0][r] * inv;
            ob[16] = oacc[1][r] * inv;
            ob[32] = oacc[2][r] * inv;
            ob[48] = oacc[3][r] * inv;
        }
    };
    epi(lsA, oA, qA);
    epi(lsB, oB, qB);
}

extern "C" void kernel_launch(void* const* d_in, const int* in_sizes, int n_in,
                              void* d_out, int out_size, void* d_ws, size_t ws_size,
                              hipStream_t stream) {
    const float* q = (const float*)d_in[0];
    const float* k = (const float*)d_in[1];
    const float* v = (const float*)d_in[2];
    // d_in[3] = attn_mask: deterministic causal, recomputed analytically.
    float* out = (float*)d_out;

    const size_t TSZ = (size_t)B_ * H_ * L_ * 64;
    u16* qp = (u16*)d_ws;
    u16* kp = qp + TSZ;
    u16* vt = kp + TSZ;

    prep_kernel<<<5120, 256, 0, stream>>>(q, k, v, qp, kp, vt);
    flash_kernel<<<512, 256, 0, stream>>>(qp, kp, vt, out);
}

// Round 9
// 172.916 us; speedup vs baseline: 1.2296x; 1.2296x over previous
//
#include <hip/hip_runtime.h>
#include <hip/hip_bf16.h>
#include <stdint.h>

#define B_ 4
#define L_ 2048
#define H_ 8
#define E_ 64
#define ALPHA 0.1f
#define LOG2E 1.44269504088896f
// Q prescale: 1/sqrt(64) * log2(e) folded into projected Q so P = exp2(S)
#define QSCALE (0.125f * LOG2E)
#define KSTR 72   // padded row stride (elements) for Kp and Vt IN GLOBAL memory;
                  // tiles are contiguous 64*144B = 9216B, DMA'd verbatim to LDS.

typedef float f32x4 __attribute__((ext_vector_type(4)));
typedef short bf16x8 __attribute__((ext_vector_type(8)));
typedef short bf16x4 __attribute__((ext_vector_type(4)));
typedef uint32_t u32;
typedef unsigned short u16;
typedef u32 u32x2 __attribute__((ext_vector_type(2)));

__device__ __forceinline__ u16 f2bf(float f) {
    u32 x = __builtin_bit_cast(u32, f);
    u32 r = x + 0x7fffu + ((x >> 16) & 1u);   // round-to-nearest-even
    return (u16)(r >> 16);
}

// pack two positive floats to packed bf16 (round-half-up; P>0, never NaN)
__device__ __forceinline__ u32 pk2bf(float a, float b) {
    u32 ua = __builtin_bit_cast(u32, a) + 0x8000u;
    u32 ub = __builtin_bit_cast(u32, b) + 0x8000u;
    return (ua >> 16) | (ub & 0xffff0000u);
}

__device__ __forceinline__ f32x4 mfma16x16x16bf16(bf16x4 a, bf16x4 b, f32x4 c) {
#if __has_builtin(__builtin_amdgcn_mfma_f32_16x16x16bf16_1k)
    return __builtin_amdgcn_mfma_f32_16x16x16bf16_1k(a, b, c, 0, 0, 0);
#elif __has_builtin(__builtin_amdgcn_mfma_f32_16x16x16_bf16)
    return __builtin_amdgcn_mfma_f32_16x16x16_bf16(a, b, c, 0, 0, 0);
#else
    f32x4 d;
    asm volatile("v_mfma_f32_16x16x16_bf16 %0, %1, %2, %3"
                 : "=v"(d) : "v"(a), "v"(b), "v"(c));
    return d;
#endif
}

// async DMA: 64 lanes x 16B, dest = wave-uniform LDS base + lane*16
__device__ __forceinline__ void dma16(const u16* g, u16* l) {
    __builtin_amdgcn_global_load_lds(
        (const __attribute__((address_space(1))) void*)g,
        (__attribute__((address_space(3))) void*)l, 16, 0, 0);
}

// ---------------------------------------------------------------------------
// Prep kernel (fused):
//  blocks [0,4096):   projection Q,K.  Q -> [bh][l][64] (unpadded, scaled by
//                     QSCALE); K -> [bh][l][KSTR] padded rows.
//  blocks [4096,5120): V transpose -> Vt tile-major [bh][stile][d][KSTR].
// Pad elements (64..71) are never written (and never read).
// ---------------------------------------------------------------------------
__global__ __launch_bounds__(256) void prep_kernel(const float* __restrict__ qin,
                                                   const float* __restrict__ kin,
                                                   const float* __restrict__ vin,
                                                   u16* __restrict__ qp,
                                                   u16* __restrict__ kp,
                                                   u16* __restrict__ vt) {
    __shared__ u16 tile[64][66];
    if (blockIdx.x < 4096) {
        const int RG = (B_ * L_ * H_) / 8;
        int wave = threadIdx.x >> 6, lane = threadIdx.x & 63;
        int g = blockIdx.x * 4 + wave;
        const float* src;
        u16* dst;
        int gr, ostr;
        float sc;
        if (g < RG) { src = qin; dst = qp; gr = g; sc = QSCALE; ostr = 64; }
        else        { src = kin; dst = kp; gr = g - RG; sc = 1.0f; ostr = KSTR; }

        int rig = lane >> 3;
        int c = (lane & 7) * 4;
        int row = gr * 8 + rig;

        const float* rp = src + (size_t)row * 64;
        float4 v0 = *(const float4*)(rp + c);
        float4 v1 = *(const float4*)(rp + c + 32);
        float f[8] = {v0.x, v0.y, v0.z, v0.w, v1.x, v1.y, v1.z, v1.w};

        float mx = 0.f;
#pragma unroll
        for (int i = 0; i < 8; ++i) mx = fmaxf(mx, fabsf(f[i]));
#pragma unroll
        for (int m = 1; m < 8; m <<= 1) mx = fmaxf(mx, __shfl_xor(mx, m));
        float thr = ALPHA * mx;

        u16 o[8];
#pragma unroll
        for (int i = 0; i < 8; ++i)
            o[i] = (fabsf(f[i]) >= thr) ? f2bf(f[i] * sc) : (u16)0;

        int b = row >> 14;
        int l = (row >> 3) & (L_ - 1);
        int h = row & 7;
        u16* orow = dst + ((size_t)(b * H_ + h) * L_ + l) * ostr;
        uint2 p0 = {(u32)o[0] | ((u32)o[1] << 16), (u32)o[2] | ((u32)o[3] << 16)};
        uint2 p1 = {(u32)o[4] | ((u32)o[5] << 16), (u32)o[6] | ((u32)o[7] << 16)};
        *(uint2*)(orow + c) = p0;
        *(uint2*)(orow + c + 32) = p1;
    } else {
        int bx = blockIdx.x - 4096;
        int bh = bx >> 5, sblk = bx & 31;
        int b = bh >> 3, h = bh & 7;
        int t = threadIdx.x;
        int s0 = sblk * 64;

#pragma unroll
        for (int p = 0; p < 2; ++p) {
            int sl = p * 32 + (t >> 3);
            int c = (t & 7) * 4;
            const float* rp = vin + (((size_t)(b * L_ + s0 + sl)) * H_ + h) * 64;
            float4 a = *(const float4*)(rp + c);
            float4 bb = *(const float4*)(rp + c + 32);
            u32* d0 = (u32*)&tile[sl][c];
            d0[0] = (u32)f2bf(a.x) | ((u32)f2bf(a.y) << 16);
            d0[1] = (u32)f2bf(a.z) | ((u32)f2bf(a.w) << 16);
            u32* d1 = (u32*)&tile[sl][c + 32];
            d1[0] = (u32)f2bf(bb.x) | ((u32)f2bf(bb.y) << 16);
            d1[1] = (u32)f2bf(bb.z) | ((u32)f2bf(bb.w) << 16);
        }
        __syncthreads();
#pragma unroll
        for (int p = 0; p < 2; ++p) {
            int d = p * 32 + (t >> 3);
            int sc2 = (t & 7) * 8;
            u16 o[8];
#pragma unroll
            for (int i = 0; i < 8; ++i) o[i] = tile[sc2 + i][d];
            uint4 val;
            val.x = (u32)o[0] | ((u32)o[1] << 16);
            val.y = (u32)o[2] | ((u32)o[3] << 16);
            val.z = (u32)o[4] | ((u32)o[5] << 16);
            val.w = (u32)o[6] | ((u32)o[7] << 16);
            // tile-major: [bh][stile=sblk][d][KSTR]
            *(uint4*)(vt + ((size_t)(bh * 32 + sblk) * 64 + d) * KSTR + sc2) = val;
        }
    }
}

// ---------------------------------------------------------------------------
// Flash attention v9: K/V tiles staged via global_load_lds DMA (no VGPR
// liveness -> compiler cannot sink the prefetch; __syncthreads' vmcnt(0) is
// the pipeline wait, with the whole compute body as slack).
// Per wave: 32 q-rows as two 16-row fragments (A at qg*128+16w, B at +64).
// Grid: 512 = 16 j x 32 bh; qg = (idx<256)? 15-j : j-8 so co-resident block
// pairs sum to 34 tiles on every CU.
// ---------------------------------------------------------------------------
__global__ __launch_bounds__(256, 2) void flash_kernel(const u16* __restrict__ Qp,
                                                       const u16* __restrict__ Kp,
                                                       const u16* __restrict__ Vt,
                                                       float* __restrict__ out) {
    __shared__ u16 kbuf[2][64 * KSTR];   // 9216 B each, verbatim global tile image
    __shared__ u16 vbuf[2][64 * KSTR];
    int t = threadIdx.x;
    int wave = t >> 6, lane = t & 63;
    int bh = blockIdx.x & 31;
    int j = blockIdx.x >> 5;                     // 0..15
    int qg = (blockIdx.x < 256) ? (15 - j) : (j - 8);
    int lo = lane & 15, quad = lane >> 4;
    int b = bh >> 3, h = bh & 7;
    int qA = qg * 128 + wave * 16;
    int qB = qA + 64;
    int dA = qg * 2;                             // frag A diagonal tile
    int T = dA + 1;                              // frag B diagonal tile (last)

    const u16* kTiles = Kp + (size_t)bh * L_ * KSTR;          // + sb*KSTR
    const u16* vTiles = Vt + (size_t)bh * 32 * 64 * KSTR;     // + stile*64*KSTR

    // DMA one 64-key tile pair (K 9KB + V 9KB = 18 x 1KB chunks) into buf
    auto stage = [&](int sb, int buf) {
        const u16* kg = kTiles + (size_t)sb * KSTR;
        const u16* vg = vTiles + (size_t)(sb >> 6) * 64 * KSTR;
        u16* kl = kbuf[buf];
        u16* vl = vbuf[buf];
        for (int i = wave; i < 18; i += 4) {
            if (i < 9) dma16(kg + i * 512 + lane * 8, kl + i * 512);
            else       dma16(vg + (i - 9) * 512 + lane * 8, vl + (i - 9) * 512);
        }
    };

    const u16* qbA = Qp + ((size_t)bh * L_ + qA + lo) * 64 + quad * 8;
    bf16x8 aQA0 = *(const bf16x8*)(qbA);
    bf16x8 aQA1 = *(const bf16x8*)(qbA + 32);
    const u16* qbB = Qp + ((size_t)bh * L_ + qB + lo) * 64 + quad * 8;
    bf16x8 aQB0 = *(const bf16x8*)(qbB);
    bf16x8 aQB1 = *(const bf16x8*)(qbB + 32);

    f32x4 oA[4], oB[4];
#pragma unroll
    for (int ni = 0; ni < 4; ++ni) {
        oA[ni] = (f32x4){0.f, 0.f, 0.f, 0.f};
        oB[ni] = (f32x4){0.f, 0.f, 0.f, 0.f};
    }
    float lsA = 0.f, lsB = 0.f;

    auto frag_proc = [&](bf16x8 k0, bf16x8 k1, const bf16x4* vf,
                         bf16x8 fq0, bf16x8 fq1, f32x4* oacc, float& lsacc,
                         bool diag) {
        f32x4 S = {0.f, 0.f, 0.f, 0.f};
        S = __builtin_amdgcn_mfma_f32_16x16x32_bf16(k0, fq0, S, 0, 0, 0);
        S = __builtin_amdgcn_mfma_f32_16x16x32_bf16(k1, fq1, S, 0, 0, 0);
        float P[4];
#pragma unroll
        for (int r = 0; r < 4; ++r) {
            float e = __builtin_amdgcn_exp2f(S[r]);
            P[r] = (diag && (quad * 4 + r > lo)) ? 0.f : e;
        }
        lsacc += (P[0] + P[1]) + (P[2] + P[3]);
        u32x2 pk = {pk2bf(P[0], P[1]), pk2bf(P[2], P[3])};
        bf16x4 aP = __builtin_bit_cast(bf16x4, pk);
#pragma unroll
        for (int ni = 0; ni < 4; ++ni)
            oacc[ni] = mfma16x16x16bf16(aP, vf[ni], oacc[ni]);
    };

    // ---- prologue: DMA tile 0 -> buf0 ----
    stage(0, 0);
    __syncthreads();

    // ---- full tiles 0..dA-1: DMA kt+1 first, compute kt, sync (vmcnt drain) ----
    for (int kt = 0; kt < dA; ++kt) {
        int cur = kt & 1;
        stage((kt + 1) << 6, cur ^ 1);
        const u16* ks = kbuf[cur];
        const u16* vs = vbuf[cur];
#pragma unroll
        for (int sub = 0; sub < 4; ++sub) {
            bf16x8 k0 = *(const bf16x8*)(ks + (sub * 16 + lo) * KSTR + quad * 8);
            bf16x8 k1 = *(const bf16x8*)(ks + (sub * 16 + lo) * KSTR + 32 + quad * 8);
            bf16x4 vf[4];
#pragma unroll
            for (int ni = 0; ni < 4; ++ni)
                vf[ni] = *(const bf16x4*)(vs + (ni * 16 + lo) * KSTR + sub * 16 + quad * 4);
            frag_proc(k0, k1, vf, aQA0, aQA1, oA, lsA, false);
            frag_proc(k0, k1, vf, aQB0, aQB1, oB, lsB, false);
        }
        __syncthreads();
    }

    // ---- tile dA: DMA tile T; frag A diagonal (subs 0..w), frag B full ----
    {
        int cur = dA & 1;
        stage(T << 6, cur ^ 1);
        const u16* ks = kbuf[cur];
        const u16* vs = vbuf[cur];
#pragma unroll
        for (int sub = 0; sub < 4; ++sub) {
            bf16x8 k0 = *(const bf16x8*)(ks + (sub * 16 + lo) * KSTR + quad * 8);
            bf16x8 k1 = *(const bf16x8*)(ks + (sub * 16 + lo) * KSTR + 32 + quad * 8);
            bf16x4 vf[4];
#pragma unroll
            for (int ni = 0; ni < 4; ++ni)
                vf[ni] = *(const bf16x4*)(vs + (ni * 16 + lo) * KSTR + sub * 16 + quad * 4);
            frag_proc(k0, k1, vf, aQB0, aQB1, oB, lsB, false);
            if (sub < wave)
                frag_proc(k0, k1, vf, aQA0, aQA1, oA, lsA, false);
            else if (sub == wave)
                frag_proc(k0, k1, vf, aQA0, aQA1, oA, lsA, true);
        }
        __syncthreads();
    }

    // ---- tile T: frag B diagonal only (subs 0..w) ----
    {
        int cur = T & 1;
        const u16* ks = kbuf[cur];
        const u16* vs = vbuf[cur];
        for (int sub = 0; sub <= wave; ++sub) {
            bf16x8 k0 = *(const bf16x8*)(ks + (sub * 16 + lo) * KSTR + quad * 8);
            bf16x8 k1 = *(const bf16x8*)(ks + (sub * 16 + lo) * KSTR + 32 + quad * 8);
            bf16x4 vf[4];
#pragma unroll
            for (int ni = 0; ni < 4; ++ni)
                vf[ni] = *(const bf16x4*)(vs + (ni * 16 + lo) * KSTR + sub * 16 + quad * 4);
            frag_proc(k0, k1, vf, aQB0, aQB1, oB, lsB, sub == wave);
        }
    }

    // ---- epilogue per fragment ----
    auto epi = [&](float ls, const f32x4* oacc, int q0f) {
        ls += __shfl_xor(ls, 16);
        ls += __shfl_xor(ls, 32);
#pragma unroll
        for (int r = 0; r < 4; ++r) {
            float lr = __shfl(ls, quad * 4 + r);
            float inv = 1.0f / lr;
            int q = q0f + quad * 4 + r;
            float* ob = out + (((size_t)(b * L_ + q)) * H_ + h) * 64 + lo;
            ob[0]  = oacc[0][r] * inv;
            ob[16] = oacc[1][r] * inv;
            ob[32] = oacc[2][r] * inv;
            ob[48] = oacc[3][r] * inv;
        }
    };
    epi(lsA, oA, qA);
    epi(lsB, oB, qB);
}

extern "C" void kernel_launch(void* const* d_in, const int* in_sizes, int n_in,
                              void* d_out, int out_size, void* d_ws, size_t ws_size,
                              hipStream_t stream) {
    const float* q = (const float*)d_in[0];
    const float* k = (const float*)d_in[1];
    const float* v = (const float*)d_in[2];
    // d_in[3] = attn_mask: deterministic causal, recomputed analytically.
    float* out = (float*)d_out;

    const size_t QSZ = (size_t)B_ * H_ * L_ * 64;     // 8.4 MB (elems)
    const size_t KSZ = (size_t)B_ * H_ * L_ * KSTR;   // 9.4 MB (elems)
    u16* qp = (u16*)d_ws;
    u16* kp = qp + QSZ;
    u16* vt = kp + KSZ;

    prep_kernel<<<5120, 256, 0, stream>>>(q, k, v, qp, kp, vt);
    flash_kernel<<<512, 256, 0, stream>>>(qp, kp, vt, out);
}

// Round 10
// 168.300 us; speedup vs baseline: 1.2633x; 1.0274x over previous
//
#include <hip/hip_runtime.h>
#include <hip/hip_bf16.h>
#include <stdint.h>

#define B_ 4
#define L_ 2048
#define H_ 8
#define E_ 64
#define ALPHA 0.1f
#define LOG2E 1.44269504088896f
// Q prescale: 1/sqrt(64) * log2(e) folded into projected Q so P = exp2(S)
#define QSCALE (0.125f * LOG2E)
#define KSTR 72   // padded row stride (elements) for Kp and Vt IN GLOBAL memory;
                  // tiles are contiguous 64*144B = 9216B, DMA'd verbatim to LDS.

typedef float f32x4 __attribute__((ext_vector_type(4)));
typedef short bf16x8 __attribute__((ext_vector_type(8)));
typedef short bf16x4 __attribute__((ext_vector_type(4)));
typedef uint32_t u32;
typedef unsigned short u16;
typedef u32 u32x2 __attribute__((ext_vector_type(2)));

__device__ __forceinline__ u16 f2bf(float f) {
    u32 x = __builtin_bit_cast(u32, f);
    u32 r = x + 0x7fffu + ((x >> 16) & 1u);   // round-to-nearest-even
    return (u16)(r >> 16);
}

// pack two positive floats to packed bf16 (round-half-up; P>0, never NaN)
__device__ __forceinline__ u32 pk2bf(float a, float b) {
    u32 ua = __builtin_bit_cast(u32, a) + 0x8000u;
    u32 ub = __builtin_bit_cast(u32, b) + 0x8000u;
    return (ua >> 16) | (ub & 0xffff0000u);
}

__device__ __forceinline__ f32x4 mfma16x16x16bf16(bf16x4 a, bf16x4 b, f32x4 c) {
#if __has_builtin(__builtin_amdgcn_mfma_f32_16x16x16bf16_1k)
    return __builtin_amdgcn_mfma_f32_16x16x16bf16_1k(a, b, c, 0, 0, 0);
#elif __has_builtin(__builtin_amdgcn_mfma_f32_16x16x16_bf16)
    return __builtin_amdgcn_mfma_f32_16x16x16_bf16(a, b, c, 0, 0, 0);
#else
    f32x4 d;
    asm volatile("v_mfma_f32_16x16x16_bf16 %0, %1, %2, %3"
                 : "=v"(d) : "v"(a), "v"(b), "v"(c));
    return d;
#endif
}

// async DMA: 64 lanes x 16B, dest = wave-uniform LDS base + lane*16
__device__ __forceinline__ void dma16(const u16* g, u16* l) {
    __builtin_amdgcn_global_load_lds(
        (const __attribute__((address_space(1))) void*)g,
        (__attribute__((address_space(3))) void*)l, 16, 0, 0);
}

// ---------------------------------------------------------------------------
// Prep kernel (fused):
//  blocks [0,4096):   projection Q,K.  Q -> [bh][l][64] (unpadded, scaled by
//                     QSCALE); K -> [bh][l][KSTR] padded rows.
//  blocks [4096,5120): V transpose -> Vt tile-major [bh][stile][d][KSTR].
// Pad elements (64..71) are never written (and never read).
// ---------------------------------------------------------------------------
__global__ __launch_bounds__(256) void prep_kernel(const float* __restrict__ qin,
                                                   const float* __restrict__ kin,
                                                   const float* __restrict__ vin,
                                                   u16* __restrict__ qp,
                                                   u16* __restrict__ kp,
                                                   u16* __restrict__ vt) {
    __shared__ u16 tile[64][66];
    if (blockIdx.x < 4096) {
        const int RG = (B_ * L_ * H_) / 8;
        int wave = threadIdx.x >> 6, lane = threadIdx.x & 63;
        int g = blockIdx.x * 4 + wave;
        const float* src;
        u16* dst;
        int gr, ostr;
        float sc;
        if (g < RG) { src = qin; dst = qp; gr = g; sc = QSCALE; ostr = 64; }
        else        { src = kin; dst = kp; gr = g - RG; sc = 1.0f; ostr = KSTR; }

        int rig = lane >> 3;
        int c = (lane & 7) * 4;
        int row = gr * 8 + rig;

        const float* rp = src + (size_t)row * 64;
        float4 v0 = *(const float4*)(rp + c);
        float4 v1 = *(const float4*)(rp + c + 32);
        float f[8] = {v0.x, v0.y, v0.z, v0.w, v1.x, v1.y, v1.z, v1.w};

        float mx = 0.f;
#pragma unroll
        for (int i = 0; i < 8; ++i) mx = fmaxf(mx, fabsf(f[i]));
#pragma unroll
        for (int m = 1; m < 8; m <<= 1) mx = fmaxf(mx, __shfl_xor(mx, m));
        float thr = ALPHA * mx;

        u16 o[8];
#pragma unroll
        for (int i = 0; i < 8; ++i)
            o[i] = (fabsf(f[i]) >= thr) ? f2bf(f[i] * sc) : (u16)0;

        int b = row >> 14;
        int l = (row >> 3) & (L_ - 1);
        int h = row & 7;
        u16* orow = dst + ((size_t)(b * H_ + h) * L_ + l) * ostr;
        uint2 p0 = {(u32)o[0] | ((u32)o[1] << 16), (u32)o[2] | ((u32)o[3] << 16)};
        uint2 p1 = {(u32)o[4] | ((u32)o[5] << 16), (u32)o[6] | ((u32)o[7] << 16)};
        *(uint2*)(orow + c) = p0;
        *(uint2*)(orow + c + 32) = p1;
    } else {
        int bx = blockIdx.x - 4096;
        int bh = bx >> 5, sblk = bx & 31;
        int b = bh >> 3, h = bh & 7;
        int t = threadIdx.x;
        int s0 = sblk * 64;

#pragma unroll
        for (int p = 0; p < 2; ++p) {
            int sl = p * 32 + (t >> 3);
            int c = (t & 7) * 4;
            const float* rp = vin + (((size_t)(b * L_ + s0 + sl)) * H_ + h) * 64;
            float4 a = *(const float4*)(rp + c);
            float4 bb = *(const float4*)(rp + c + 32);
            u32* d0 = (u32*)&tile[sl][c];
            d0[0] = (u32)f2bf(a.x) | ((u32)f2bf(a.y) << 16);
            d0[1] = (u32)f2bf(a.z) | ((u32)f2bf(a.w) << 16);
            u32* d1 = (u32*)&tile[sl][c + 32];
            d1[0] = (u32)f2bf(bb.x) | ((u32)f2bf(bb.y) << 16);
            d1[1] = (u32)f2bf(bb.z) | ((u32)f2bf(bb.w) << 16);
        }
        __syncthreads();
#pragma unroll
        for (int p = 0; p < 2; ++p) {
            int d = p * 32 + (t >> 3);
            int sc2 = (t & 7) * 8;
            u16 o[8];
#pragma unroll
            for (int i = 0; i < 8; ++i) o[i] = tile[sc2 + i][d];
            uint4 val;
            val.x = (u32)o[0] | ((u32)o[1] << 16);
            val.y = (u32)o[2] | ((u32)o[3] << 16);
            val.z = (u32)o[4] | ((u32)o[5] << 16);
            val.w = (u32)o[6] | ((u32)o[7] << 16);
            // tile-major: [bh][stile=sblk][d][KSTR]
            *(uint4*)(vt + ((size_t)(bh * 32 + sblk) * 64 + d) * KSTR + sc2) = val;
        }
    }
}

// ---------------------------------------------------------------------------
// Flash attention v10: v9's global_load_lds DMA staging + v6's 1024-block
// grid (4 blocks/CU, 16 waves/CU) for time-local latency hiding.
// Grid: 1024 = 32 qq-groups x 32 bh; wave w owns q-tile 4qq+w (16 rows);
// all waves run tiles 0..qq (uniform barrier count). qq interleaved so each
// CU's 4 resident blocks sum to 66 tile-units. __syncthreads' vmcnt(0) drain
// is the DMA pipeline wait, with the whole compute body as slack.
// ---------------------------------------------------------------------------
__global__ __launch_bounds__(256, 4) void flash_kernel(const u16* __restrict__ Qp,
                                                       const u16* __restrict__ Kp,
                                                       const u16* __restrict__ Vt,
                                                       float* __restrict__ out) {
    __shared__ u16 kbuf[2][64 * KSTR];   // 9216 B each, verbatim global tile image
    __shared__ u16 vbuf[2][64 * KSTR];
    int t = threadIdx.x;
    int wave = t >> 6, lane = t & 63;
    int bh = blockIdx.x & 31;            // fastest -> bh mod 8 pins XCD (L2 locality)
    int r5 = blockIdx.x >> 5;            // 0..31
    int g = r5 & 7, kr = r5 >> 3;
    // per-CU-balanced interleave: sums of (qq+1) over the 4 rounds = 66 for all g
    int qq = (kr == 0) ? (31 - g) : (kr == 1) ? (16 + g) : (kr == 2) ? (15 - g) : g;
    int lo = lane & 15, quad = lane >> 4;
    int q0 = qq * 64 + wave * 16;
    int b = bh >> 3, h = bh & 7;

    const u16* kTiles = Kp + (size_t)bh * L_ * KSTR;          // + sb*KSTR
    const u16* vTiles = Vt + (size_t)bh * 32 * 64 * KSTR;     // + stile*64*KSTR

    // DMA one 64-key tile pair (K 9KB + V 9KB = 18 x 1KB chunks) into buf
    auto stage = [&](int sb, int buf) {
        const u16* kg = kTiles + (size_t)sb * KSTR;
        const u16* vg = vTiles + (size_t)(sb >> 6) * 64 * KSTR;
        u16* kl = kbuf[buf];
        u16* vl = vbuf[buf];
        for (int i = wave; i < 18; i += 4) {
            if (i < 9) dma16(kg + i * 512 + lane * 8, kl + i * 512);
            else       dma16(vg + (i - 9) * 512 + lane * 8, vl + (i - 9) * 512);
        }
    };

    // Q fragment (B-operand of the S^T MFMA)
    const u16* qbase = Qp + ((size_t)bh * L_ + q0 + lo) * 64 + quad * 8;
    bf16x8 aQ0 = *(const bf16x8*)(qbase);
    bf16x8 aQ1 = *(const bf16x8*)(qbase + 32);

    f32x4 o[4];
#pragma unroll
    for (int ni = 0; ni < 4; ++ni) o[ni] = (f32x4){0.f, 0.f, 0.f, 0.f};
    float ls = 0.f;   // per-lane partial of l[q=q0+lo] (this quad's s-slices)

    auto frag_proc = [&](const u16* ks, const u16* vs, int sub, bool diag) {
        bf16x8 k0 = *(const bf16x8*)(ks + (sub * 16 + lo) * KSTR + quad * 8);
        bf16x8 k1 = *(const bf16x8*)(ks + (sub * 16 + lo) * KSTR + 32 + quad * 8);
        f32x4 S = {0.f, 0.f, 0.f, 0.f};
        S = __builtin_amdgcn_mfma_f32_16x16x32_bf16(k0, aQ0, S, 0, 0, 0);
        S = __builtin_amdgcn_mfma_f32_16x16x32_bf16(k1, aQ1, S, 0, 0, 0);

        bf16x4 vf[4];
#pragma unroll
        for (int ni = 0; ni < 4; ++ni)
            vf[ni] = *(const bf16x4*)(vs + (ni * 16 + lo) * KSTR + sub * 16 + quad * 4);

        float P[4];
#pragma unroll
        for (int r = 0; r < 4; ++r) {
            float e = __builtin_amdgcn_exp2f(S[r]);
            P[r] = (diag && (quad * 4 + r > lo)) ? 0.f : e;
        }
        ls += (P[0] + P[1]) + (P[2] + P[3]);
        u32x2 pk = {pk2bf(P[0], P[1]), pk2bf(P[2], P[3])};
        bf16x4 aP = __builtin_bit_cast(bf16x4, pk);
#pragma unroll
        for (int ni = 0; ni < 4; ++ni)
            o[ni] = mfma16x16x16bf16(aP, vf[ni], o[ni]);
    };

    // ---- prologue: DMA tile 0 -> buf0 ----
    stage(0, 0);
    __syncthreads();

    // ---- full tiles 0..qq-1: DMA kt+1 first, compute kt, sync (vmcnt drain) ----
    for (int kt = 0; kt < qq; ++kt) {
        int cur = kt & 1;
        stage((kt + 1) << 6, cur ^ 1);
        const u16* ks = kbuf[cur];
        const u16* vs = vbuf[cur];
#pragma unroll
        for (int sub = 0; sub < 4; ++sub) frag_proc(ks, vs, sub, false);
        __syncthreads();
    }

    // ---- diagonal tile qq: subtiles 0..wave (sub>wave fully masked -> skip) ----
    {
        int cur = qq & 1;
        const u16* ks = kbuf[cur];
        const u16* vs = vbuf[cur];
        for (int sub = 0; sub < wave; ++sub) frag_proc(ks, vs, sub, false);
        frag_proc(ks, vs, wave, true);
    }

    // ---- epilogue: full l on every lane, normalize, store fp32 ----
    ls += __shfl_xor(ls, 16);
    ls += __shfl_xor(ls, 32);
#pragma unroll
    for (int r = 0; r < 4; ++r) {
        float lr = __shfl(ls, quad * 4 + r);   // l for output row q0+quad*4+r
        float inv = 1.0f / lr;
        int q = q0 + quad * 4 + r;
        float* ob = out + (((size_t)(b * L_ + q)) * H_ + h) * 64 + lo;
        ob[0]  = o[0][r] * inv;
        ob[16] = o[1][r] * inv;
        ob[32] = o[2][r] * inv;
        ob[48] = o[3][r] * inv;
    }
}

extern "C" void kernel_launch(void* const* d_in, const int* in_sizes, int n_in,
                              void* d_out, int out_size, void* d_ws, size_t ws_size,
                              hipStream_t stream) {
    const float* q = (const float*)d_in[0];
    const float* k = (const float*)d_in[1];
    const float* v = (const float*)d_in[2];
    // d_in[3] = attn_mask: deterministic causal, recomputed analytically.
    float* out = (float*)d_out;

    const size_t QSZ = (size_t)B_ * H_ * L_ * 64;     // elements
    const size_t KSZ = (size_t)B_ * H_ * L_ * KSTR;   // elements
    u16* qp = (u16*)d_ws;
    u16* kp = qp + QSZ;
    u16* vt = kp + KSZ;

    prep_kernel<<<5120, 256, 0, stream>>>(q, k, v, qp, kp, vt);
    flash_kernel<<<1024, 256, 0, stream>>>(qp, kp, vt, out);
}